// Round 2
// baseline (106.708 us; speedup 1.0000x reference)
//
#include <hip/hip_runtime.h>
#include <hip/hip_bf16.h>

// Problem constants (EdgeQProj): B=64, N=64, E=512, OBJ_DIM=2048, Q_DIM=1024,
// HID=512, KS=8. M_edges = B*E = 32768.

using bf16x8 = __attribute__((ext_vector_type(8))) __bf16;
using f32x4  = __attribute__((ext_vector_type(4))) float;

__device__ __forceinline__ unsigned short f2bf(float f) {
    unsigned int u = __float_as_uint(f);
    unsigned int r = (u + 0x7FFFu + ((u >> 16) & 1u)) >> 16;  // RNE
    return (unsigned short)r;
}

// ---------------------------------------------------------------------------
// 1) node_feats fp32 [4096][2048] -> bf16 (workspace)
__global__ __launch_bounds__(256) void cvt_a(const float* __restrict__ in,
                                             unsigned short* __restrict__ out) {
    int tid = blockIdx.x * 256 + threadIdx.x;          // 2048*256 = 524288
    for (int p = tid; p < 2097152; p += 524288) {      // 8388608/4 float4s
        float4 v = *(const float4*)(in + (size_t)p * 4);
        ushort4 o;
        o.x = f2bf(v.x); o.y = f2bf(v.y); o.z = f2bf(v.z); o.w = f2bf(v.w);
        *(ushort4*)(out + (size_t)p * 4) = o;
    }
}

// ---------------------------------------------------------------------------
// 2) W_obj fp32 [2048][512] -> W_T bf16 [512][2048]  (tiled transpose)
__global__ __launch_bounds__(256) void cvt_bt(const float* __restrict__ W,
                                              unsigned short* __restrict__ WT) {
    __shared__ float lds[32][33];
    int k0 = blockIdx.x * 32, n0 = blockIdx.y * 32;
    int tx = threadIdx.x & 31, ty = threadIdx.x >> 5;  // ty 0..7
#pragma unroll
    for (int j = 0; j < 4; ++j)
        lds[ty + j * 8][tx] = W[(size_t)(k0 + ty + j * 8) * 512 + n0 + tx];
    __syncthreads();
#pragma unroll
    for (int j = 0; j < 4; ++j)
        WT[(size_t)(n0 + ty + j * 8) * 2048 + k0 + tx] = f2bf(lds[tx][ty + j * 8]);
}

// ---------------------------------------------------------------------------
// 3) GEMM1: node_h[4096][512] = relu(A_bf16[4096][2048] @ W_T^T + b_obj)
//    BM=128 BN=64 BK=64 (2 ksubs of 32), 512 threads = 8 waves (4x2),
//    wave tile 32x32 (2x2 frags of 16x16x32 MFMA). Padded LDS rows (40 elems)
//    -> 2-way bank aliasing on ds_read_b128 (free).
#define LDK 40
__global__ __launch_bounds__(512, 2) void gemm1(const unsigned short* __restrict__ A,
                                                const unsigned short* __restrict__ BT,
                                                const float* __restrict__ bias,
                                                float* __restrict__ C) {
    __shared__ __align__(16) unsigned short Asm[2][128][LDK];
    __shared__ __align__(16) unsigned short Bsm[2][64][LDK];

    // XCD-aware swizzle: grid=256 (%8==0, bijective). XCD x -> 32 consecutive
    // swz ids = 4 m-panels x full N  => A 4*0.5MB + B 2MB ~ L2-resident.
    int bid = blockIdx.x;
    int swz = (bid & 7) * 32 + (bid >> 3);
    int by = swz >> 3, bx = swz & 7;
    int m0 = by * 128, n0 = bx * 64;

    int t = threadIdx.x;
    int lane = t & 63, w = t >> 6;
    int wm = w >> 1, wn = w & 1;              // wave grid 4x2
    int l15 = lane & 15, l16 = lane >> 4;

    f32x4 acc[2][2];
#pragma unroll
    for (int i = 0; i < 2; ++i)
#pragma unroll
        for (int j = 0; j < 2; ++j) acc[i][j] = (f32x4){0.f, 0.f, 0.f, 0.f};

    for (int k0 = 0; k0 < 2048; k0 += 64) {
        // ---- stage A (1024 x 16B chunks) + B (512 chunks), reg-staged ----
#pragma unroll
        for (int j = 0; j < 2; ++j) {
            int c = j * 512 + t;
            int row = c >> 3, kc = c & 7;
            uint4 v = *(const uint4*)(A + (size_t)(m0 + row) * 2048 + k0 + kc * 8);
            *(uint4*)(&Asm[kc >> 2][row][(kc & 3) * 8]) = v;
        }
        {
            int row = t >> 3, kc = t & 7;
            uint4 v = *(const uint4*)(BT + (size_t)(n0 + row) * 2048 + k0 + kc * 8);
            *(uint4*)(&Bsm[kc >> 2][row][(kc & 3) * 8]) = v;
        }
        __syncthreads();
        // ---- compute: 2 ksubs x (2x2) MFMAs ----
#pragma unroll
        for (int s = 0; s < 2; ++s) {
            bf16x8 a0 = *(const bf16x8*)(&Asm[s][wm * 32 + l15][l16 * 8]);
            bf16x8 a1 = *(const bf16x8*)(&Asm[s][wm * 32 + 16 + l15][l16 * 8]);
            bf16x8 b0 = *(const bf16x8*)(&Bsm[s][wn * 32 + l15][l16 * 8]);
            bf16x8 b1 = *(const bf16x8*)(&Bsm[s][wn * 32 + 16 + l15][l16 * 8]);
            acc[0][0] = __builtin_amdgcn_mfma_f32_16x16x32_bf16(a0, b0, acc[0][0], 0, 0, 0);
            acc[0][1] = __builtin_amdgcn_mfma_f32_16x16x32_bf16(a0, b1, acc[0][1], 0, 0, 0);
            acc[1][0] = __builtin_amdgcn_mfma_f32_16x16x32_bf16(a1, b0, acc[1][0], 0, 0, 0);
            acc[1][1] = __builtin_amdgcn_mfma_f32_16x16x32_bf16(a1, b1, acc[1][1], 0, 0, 0);
        }
        __syncthreads();
    }
    // ---- epilogue: bias + relu; D layout col=lane&15, row=(lane>>4)*4+j ----
#pragma unroll
    for (int fm = 0; fm < 2; ++fm)
#pragma unroll
        for (int fn = 0; fn < 2; ++fn) {
            int col = n0 + wn * 32 + fn * 16 + l15;
            float bv = bias[col];
#pragma unroll
            for (int j = 0; j < 4; ++j) {
                int row = m0 + wm * 32 + fm * 16 + l16 * 4 + j;
                float v = acc[fm][fn][j] + bv;
                C[(size_t)row * 512 + col] = v > 0.f ? v : 0.f;
            }
        }
}

// ---------------------------------------------------------------------------
// 4) GEMM2 (fp32, K-split 8): part[ks][64][4096] partial of q_feats @ W_q
//    grid (64 col-tiles, 8 ksplits) x 256 thr; thread = 4 rows x 4 cols.
__global__ __launch_bounds__(256) void gemm2(const float* __restrict__ qf,
                                             const float* __restrict__ Wq,
                                             float* __restrict__ part) {
    int t = threadIdx.x;
    int tx = t & 15, ty = t >> 4;
    int c = blockIdx.x * 64 + tx * 4;
    int k0 = blockIdx.y * 128;

    f32x4 acc[4];
#pragma unroll
    for (int j = 0; j < 4; ++j) acc[j] = (f32x4){0.f, 0.f, 0.f, 0.f};

    const float* qb = qf + (size_t)(ty * 4) * 1024 + k0;
    const float* wb = Wq + (size_t)k0 * 4096 + c;

    for (int kk = 0; kk < 128; kk += 4) {
        float4 q0 = *(const float4*)(qb + 0 * 1024 + kk);
        float4 q1 = *(const float4*)(qb + 1 * 1024 + kk);
        float4 q2 = *(const float4*)(qb + 2 * 1024 + kk);
        float4 q3 = *(const float4*)(qb + 3 * 1024 + kk);
        f32x4 w0 = *(const f32x4*)(wb + (size_t)(kk + 0) * 4096);
        f32x4 w1 = *(const f32x4*)(wb + (size_t)(kk + 1) * 4096);
        f32x4 w2 = *(const f32x4*)(wb + (size_t)(kk + 2) * 4096);
        f32x4 w3 = *(const f32x4*)(wb + (size_t)(kk + 3) * 4096);
        acc[0] += q0.x * w0; acc[0] += q0.y * w1; acc[0] += q0.z * w2; acc[0] += q0.w * w3;
        acc[1] += q1.x * w0; acc[1] += q1.y * w1; acc[1] += q1.z * w2; acc[1] += q1.w * w3;
        acc[2] += q2.x * w0; acc[2] += q2.y * w1; acc[2] += q2.z * w2; acc[2] += q2.w * w3;
        acc[3] += q3.x * w0; acc[3] += q3.y * w1; acc[3] += q3.z * w2; acc[3] += q3.w * w3;
    }
    float* pb = part + (size_t)blockIdx.y * 262144 + (size_t)(ty * 4) * 4096 + c;
#pragma unroll
    for (int j = 0; j < 4; ++j) *(f32x4*)(pb + (size_t)j * 4096) = acc[j];
}

// 5) reduce partials + bias + relu -> q_h[64][4096]
__global__ __launch_bounds__(256) void finish_q(const float* __restrict__ part,
                                                const float* __restrict__ bq,
                                                float* __restrict__ q_h) {
    int base = (blockIdx.x * 256 + threadIdx.x) * 4;
    f32x4 a = (f32x4){0.f, 0.f, 0.f, 0.f};
#pragma unroll
    for (int s = 0; s < 8; ++s) a += *(const f32x4*)(part + (size_t)s * 262144 + base);
    f32x4 bb = *(const f32x4*)(bq + (base & 4095));
#pragma unroll
    for (int j = 0; j < 4; ++j) {
        float v = a[j] + bb[j];
        a[j] = v > 0.f ? v : 0.f;
    }
    *(f32x4*)(q_h + base) = a;
}

// 6) inv_norm[b][k] = 1/sqrt(sum_h q_h[b][h*8+k]^2)
__global__ __launch_bounds__(256) void norms_k(const float* __restrict__ q_h,
                                               float* __restrict__ inv_norm) {
    __shared__ float red[4][8];
    int b = blockIdx.x, t = threadIdx.x;
    const float* row = q_h + (size_t)b * 4096 + t * 16;
    float sq[8] = {0.f, 0.f, 0.f, 0.f, 0.f, 0.f, 0.f, 0.f};
#pragma unroll
    for (int j = 0; j < 4; ++j) {
        float4 v = *(const float4*)(row + j * 4);
        sq[(j * 4 + 0) & 7] += v.x * v.x;
        sq[(j * 4 + 1) & 7] += v.y * v.y;
        sq[(j * 4 + 2) & 7] += v.z * v.z;
        sq[(j * 4 + 3) & 7] += v.w * v.w;
    }
#pragma unroll
    for (int k = 0; k < 8; ++k) {
        float v = sq[k];
        v += __shfl_xor(v, 1);  v += __shfl_xor(v, 2);  v += __shfl_xor(v, 4);
        v += __shfl_xor(v, 8);  v += __shfl_xor(v, 16); v += __shfl_xor(v, 32);
        sq[k] = v;
    }
    int lane = t & 63, wv = t >> 6;
    if (lane == 0) {
#pragma unroll
        for (int k = 0; k < 8; ++k) red[wv][k] = sq[k];
    }
    __syncthreads();
    if (t < 8) {
        float s = red[0][t] + red[1][t] + red[2][t] + red[3][t];
        inv_norm[b * 8 + t] = 1.0f / sqrtf(s);
    }
}

// ---------------------------------------------------------------------------
// 7) edge kernel: wave handles 8 edges of one batch; q row lives in 64 VGPRs.
__global__ __launch_bounds__(256) void edge_k(const int* __restrict__ idxs,
                                              const float* __restrict__ node_h,
                                              const float* __restrict__ q_h,
                                              const float* __restrict__ inv_norm,
                                              float* __restrict__ out) {
    int t = threadIdx.x;
    int lane = t & 63;
    int gw = blockIdx.x * 4 + (t >> 6);   // 0..4095
    int m0 = gw * 8;
    int b = m0 >> 9;                       // edges sorted by batch: m//E

    // lane l holds q_h[b][l*64 .. l*64+63]  (h = l*8+i, k = 0..7)
    const float* qrow = q_h + (size_t)b * 4096 + lane * 64;
    float q[64];
#pragma unroll
    for (int i = 0; i < 16; ++i) {
        float4 v = *(const float4*)(qrow + i * 4);
        q[i * 4 + 0] = v.x; q[i * 4 + 1] = v.y; q[i * 4 + 2] = v.z; q[i * 4 + 3] = v.w;
    }
    float4 inv0 = *(const float4*)(inv_norm + b * 8);
    float4 inv1 = *(const float4*)(inv_norm + b * 8 + 4);
    const float* nb = node_h + (size_t)b * 64 * 512;

#pragma unroll 2
    for (int e = 0; e < 8; ++e) {
        int m = m0 + e;
        int idx = idxs[m];
        int r = idx & 4095;
        int src = r >> 6, dst = r & 63;
        const float* sp = nb + (size_t)src * 512 + lane * 8;
        const float* dp = nb + (size_t)dst * 512 + lane * 8;
        float4 s0 = *(const float4*)(sp), s1 = *(const float4*)(sp + 4);
        float4 d0 = *(const float4*)(dp), d1 = *(const float4*)(dp + 4);
        float obj[8] = {s0.x + d0.x, s0.y + d0.y, s0.z + d0.z, s0.w + d0.w,
                        s1.x + d1.x, s1.y + d1.y, s1.z + d1.z, s1.w + d1.w};
        float acc[8] = {0.f, 0.f, 0.f, 0.f, 0.f, 0.f, 0.f, 0.f};
#pragma unroll
        for (int i = 0; i < 8; ++i)
#pragma unroll
            for (int k = 0; k < 8; ++k)
                acc[k] = fmaf(obj[i], q[i * 8 + k], acc[k]);
#pragma unroll
        for (int k = 0; k < 8; ++k) {
            float v = acc[k];
            v += __shfl_xor(v, 1);  v += __shfl_xor(v, 2);  v += __shfl_xor(v, 4);
            v += __shfl_xor(v, 8);  v += __shfl_xor(v, 16); v += __shfl_xor(v, 32);
            acc[k] = v;
        }
        if (lane == 0) {
            float4 o0 = {acc[0] * inv0.x, acc[1] * inv0.y, acc[2] * inv0.z, acc[3] * inv0.w};
            float4 o1 = {acc[4] * inv1.x, acc[5] * inv1.y, acc[6] * inv1.z, acc[7] * inv1.w};
            *(float4*)(out + (size_t)m * 8) = o0;
            *(float4*)(out + (size_t)m * 8 + 4) = o1;
        }
    }
}

// ---------------------------------------------------------------------------
extern "C" void kernel_launch(void* const* d_in, const int* in_sizes, int n_in,
                              void* d_out, int out_size, void* d_ws, size_t ws_size,
                              hipStream_t stream) {
    const float* node_feats = (const float*)d_in[0];  // [64][64][2048]
    const float* q_feats    = (const float*)d_in[1];  // [64][1024]
    const int*   indexes    = (const int*)d_in[2];    // [32768]
    const float* W_obj      = (const float*)d_in[3];  // [2048][512]
    const float* b_obj      = (const float*)d_in[4];  // [512]
    const float* W_q        = (const float*)d_in[5];  // [1024][4096]
    const float* b_q        = (const float*)d_in[6];  // [4096]
    float* out = (float*)d_out;                       // [32768][8]

    char* ws = (char*)d_ws;
    // A bf16 region (16.78MB) is reused as gemm2 partials (8.39MB) after gemm1.
    unsigned short* A_bf16 = (unsigned short*)(ws + 0);
    unsigned short* W_T    = (unsigned short*)(ws + 16777216);
    float* node_h          = (float*)(ws + 18874368);  // 8.39MB
    float* q_h             = (float*)(ws + 27262976);  // 1.05MB
    float* inv_norm        = (float*)(ws + 28311552);  // 2KB
    float* part            = (float*)(ws + 0);         // aliases A_bf16

    cvt_a<<<2048, 256, 0, stream>>>(node_feats, A_bf16);
    cvt_bt<<<dim3(64, 16), 256, 0, stream>>>(W_obj, W_T);
    gemm1<<<256, 512, 0, stream>>>(A_bf16, W_T, b_obj, node_h);
    gemm2<<<dim3(64, 8), 256, 0, stream>>>(q_feats, W_q, part);   // after gemm1 (aliasing)
    finish_q<<<256, 256, 0, stream>>>(part, b_q, q_h);
    norms_k<<<64, 256, 0, stream>>>(q_h, inv_norm);
    edge_k<<<1024, 256, 0, stream>>>(indexes, node_h, q_h, inv_norm, out);
}

// Round 3
// 105.750 us; speedup vs baseline: 1.0091x; 1.0091x over previous
//
#include <hip/hip_runtime.h>
#include <hip/hip_bf16.h>

// Problem constants (EdgeQProj): B=64, N=64, E=512, OBJ_DIM=2048, Q_DIM=1024,
// HID=512, KS=8. M_edges = B*E = 32768.

using bf16x8 = __attribute__((ext_vector_type(8))) __bf16;
using f32x4  = __attribute__((ext_vector_type(4))) float;

__device__ __forceinline__ unsigned short f2bf(float f) {
    unsigned int u = __float_as_uint(f);
    unsigned int r = (u + 0x7FFFu + ((u >> 16) & 1u)) >> 16;  // RNE
    return (unsigned short)r;
}

// ---------------------------------------------------------------------------
// 1) node_feats fp32 [4096][2048] -> bf16 (workspace)
__global__ __launch_bounds__(256) void cvt_a(const float* __restrict__ in,
                                             unsigned short* __restrict__ out) {
    int tid = blockIdx.x * 256 + threadIdx.x;          // 2048*256 = 524288
    for (int p = tid; p < 2097152; p += 524288) {      // 8388608/4 float4s
        float4 v = *(const float4*)(in + (size_t)p * 4);
        ushort4 o;
        o.x = f2bf(v.x); o.y = f2bf(v.y); o.z = f2bf(v.z); o.w = f2bf(v.w);
        *(ushort4*)(out + (size_t)p * 4) = o;
    }
}

// ---------------------------------------------------------------------------
// 2) W_obj fp32 [2048][512] -> W_T bf16 [512][2048]  (tiled transpose)
__global__ __launch_bounds__(256) void cvt_bt(const float* __restrict__ W,
                                              unsigned short* __restrict__ WT) {
    __shared__ float lds[32][33];
    int k0 = blockIdx.x * 32, n0 = blockIdx.y * 32;
    int tx = threadIdx.x & 31, ty = threadIdx.x >> 5;  // ty 0..7
#pragma unroll
    for (int j = 0; j < 4; ++j)
        lds[ty + j * 8][tx] = W[(size_t)(k0 + ty + j * 8) * 512 + n0 + tx];
    __syncthreads();
#pragma unroll
    for (int j = 0; j < 4; ++j)
        WT[(size_t)(n0 + ty + j * 8) * 2048 + k0 + tx] = f2bf(lds[tx][ty + j * 8]);
}

// ---------------------------------------------------------------------------
// 3) GEMM1: node_h[4096][512] = relu(A_bf16[4096][2048] @ W_T^T + b_obj)
//    BM=128 BN=64 BK=64 (2 ksubs of 32), 512 threads = 8 waves (4x2),
//    wave tile 32x32 (2x2 frags of 16x16x32 MFMA). Padded LDS rows (40 elems)
//    -> 2-way bank aliasing on ds_read_b128 (free).
#define LDK 40
__global__ __launch_bounds__(512, 2) void gemm1(const unsigned short* __restrict__ A,
                                                const unsigned short* __restrict__ BT,
                                                const float* __restrict__ bias,
                                                float* __restrict__ C) {
    __shared__ __align__(16) unsigned short Asm[2][128][LDK];
    __shared__ __align__(16) unsigned short Bsm[2][64][LDK];

    // XCD-aware swizzle: grid=256 (%8==0, bijective). XCD x -> 32 consecutive
    // swz ids = 4 m-panels x full N  => A 4*0.5MB + B 2MB ~ L2-resident.
    int bid = blockIdx.x;
    int swz = (bid & 7) * 32 + (bid >> 3);
    int by = swz >> 3, bx = swz & 7;
    int m0 = by * 128, n0 = bx * 64;

    int t = threadIdx.x;
    int lane = t & 63, w = t >> 6;
    int wm = w >> 1, wn = w & 1;              // wave grid 4x2
    int l15 = lane & 15, l16 = lane >> 4;

    f32x4 acc[2][2];
#pragma unroll
    for (int i = 0; i < 2; ++i)
#pragma unroll
        for (int j = 0; j < 2; ++j) acc[i][j] = (f32x4){0.f, 0.f, 0.f, 0.f};

    for (int k0 = 0; k0 < 2048; k0 += 64) {
        // ---- stage A (1024 x 16B chunks) + B (512 chunks), reg-staged ----
#pragma unroll
        for (int j = 0; j < 2; ++j) {
            int c = j * 512 + t;
            int row = c >> 3, kc = c & 7;
            uint4 v = *(const uint4*)(A + (size_t)(m0 + row) * 2048 + k0 + kc * 8);
            *(uint4*)(&Asm[kc >> 2][row][(kc & 3) * 8]) = v;
        }
        {
            int row = t >> 3, kc = t & 7;
            uint4 v = *(const uint4*)(BT + (size_t)(n0 + row) * 2048 + k0 + kc * 8);
            *(uint4*)(&Bsm[kc >> 2][row][(kc & 3) * 8]) = v;
        }
        __syncthreads();
        // ---- compute: 2 ksubs x (2x2) MFMAs ----
#pragma unroll
        for (int s = 0; s < 2; ++s) {
            bf16x8 a0 = *(const bf16x8*)(&Asm[s][wm * 32 + l15][l16 * 8]);
            bf16x8 a1 = *(const bf16x8*)(&Asm[s][wm * 32 + 16 + l15][l16 * 8]);
            bf16x8 b0 = *(const bf16x8*)(&Bsm[s][wn * 32 + l15][l16 * 8]);
            bf16x8 b1 = *(const bf16x8*)(&Bsm[s][wn * 32 + 16 + l15][l16 * 8]);
            acc[0][0] = __builtin_amdgcn_mfma_f32_16x16x32_bf16(a0, b0, acc[0][0], 0, 0, 0);
            acc[0][1] = __builtin_amdgcn_mfma_f32_16x16x32_bf16(a0, b1, acc[0][1], 0, 0, 0);
            acc[1][0] = __builtin_amdgcn_mfma_f32_16x16x32_bf16(a1, b0, acc[1][0], 0, 0, 0);
            acc[1][1] = __builtin_amdgcn_mfma_f32_16x16x32_bf16(a1, b1, acc[1][1], 0, 0, 0);
        }
        __syncthreads();
    }
    // ---- epilogue: bias + relu; D layout col=lane&15, row=(lane>>4)*4+j ----
#pragma unroll
    for (int fm = 0; fm < 2; ++fm)
#pragma unroll
        for (int fn = 0; fn < 2; ++fn) {
            int col = n0 + wn * 32 + fn * 16 + l15;
            float bv = bias[col];
#pragma unroll
            for (int j = 0; j < 4; ++j) {
                int row = m0 + wm * 32 + fm * 16 + l16 * 4 + j;
                float v = acc[fm][fn][j] + bv;
                C[(size_t)row * 512 + col] = v > 0.f ? v : 0.f;
            }
        }
}

// ---------------------------------------------------------------------------
// 4) GEMM2 rewrite (streaming, K-split 4): part[z][64][4096] partials of
//    q_feats @ W_q.  Block = 256 thr; thread owns 4 consecutive cols (f32x4)
//    x 4 rows.  Wave load = 64 lanes x 16B = 1KB contiguous W_q row chunk.
//    q slice (4 rows x 256 k) staged in LDS, read back as broadcast b128.
//    grid = (4 colblocks, 16 rowgroups, 4 ksplits) = 256 blocks.
__global__ __launch_bounds__(256) void gemm2(const float* __restrict__ qf,
                                             const float* __restrict__ Wq,
                                             float* __restrict__ part) {
    __shared__ float qs[4][256];
    int t = threadIdx.x;
    int c  = blockIdx.x * 1024 + t * 4;
    int r0 = blockIdx.y * 4;
    int k0 = blockIdx.z * 256;

    // stage q: 4 rows x 256 k
#pragma unroll
    for (int i = 0; i < 4; ++i)
        qs[i][t] = qf[(size_t)(r0 + i) * 1024 + k0 + t];
    __syncthreads();

    f32x4 acc[4];
#pragma unroll
    for (int i = 0; i < 4; ++i) acc[i] = (f32x4){0.f, 0.f, 0.f, 0.f};

    const float* wb = Wq + (size_t)k0 * 4096 + c;
#pragma unroll 2
    for (int kk = 0; kk < 256; kk += 4) {
        f32x4 w0 = *(const f32x4*)(wb + (size_t)(kk + 0) * 4096);
        f32x4 w1 = *(const f32x4*)(wb + (size_t)(kk + 1) * 4096);
        f32x4 w2 = *(const f32x4*)(wb + (size_t)(kk + 2) * 4096);
        f32x4 w3 = *(const f32x4*)(wb + (size_t)(kk + 3) * 4096);
        f32x4 q0 = *(const f32x4*)(&qs[0][kk]);
        f32x4 q1 = *(const f32x4*)(&qs[1][kk]);
        f32x4 q2 = *(const f32x4*)(&qs[2][kk]);
        f32x4 q3 = *(const f32x4*)(&qs[3][kk]);
        acc[0] += q0.x * w0; acc[0] += q0.y * w1; acc[0] += q0.z * w2; acc[0] += q0.w * w3;
        acc[1] += q1.x * w0; acc[1] += q1.y * w1; acc[1] += q1.z * w2; acc[1] += q1.w * w3;
        acc[2] += q2.x * w0; acc[2] += q2.y * w1; acc[2] += q2.z * w2; acc[2] += q2.w * w3;
        acc[3] += q3.x * w0; acc[3] += q3.y * w1; acc[3] += q3.z * w2; acc[3] += q3.w * w3;
    }
    float* pb = part + (size_t)blockIdx.z * 262144 + (size_t)r0 * 4096 + c;
#pragma unroll
    for (int i = 0; i < 4; ++i) *(f32x4*)(pb + (size_t)i * 4096) = acc[i];
}

// 5) reduce partials + bias + relu -> q_h[64][4096]
__global__ __launch_bounds__(256) void finish_q(const float* __restrict__ part,
                                                const float* __restrict__ bq,
                                                float* __restrict__ q_h) {
    int base = (blockIdx.x * 256 + threadIdx.x) * 4;
    f32x4 a = (f32x4){0.f, 0.f, 0.f, 0.f};
#pragma unroll
    for (int s = 0; s < 4; ++s) a += *(const f32x4*)(part + (size_t)s * 262144 + base);
    f32x4 bb = *(const f32x4*)(bq + (base & 4095));
#pragma unroll
    for (int j = 0; j < 4; ++j) {
        float v = a[j] + bb[j];
        a[j] = v > 0.f ? v : 0.f;
    }
    *(f32x4*)(q_h + base) = a;
}

// 6) inv_norm[b][k] = 1/sqrt(sum_h q_h[b][h*8+k]^2)
__global__ __launch_bounds__(256) void norms_k(const float* __restrict__ q_h,
                                               float* __restrict__ inv_norm) {
    __shared__ float red[4][8];
    int b = blockIdx.x, t = threadIdx.x;
    const float* row = q_h + (size_t)b * 4096 + t * 16;
    float sq[8] = {0.f, 0.f, 0.f, 0.f, 0.f, 0.f, 0.f, 0.f};
#pragma unroll
    for (int j = 0; j < 4; ++j) {
        float4 v = *(const float4*)(row + j * 4);
        sq[(j * 4 + 0) & 7] += v.x * v.x;
        sq[(j * 4 + 1) & 7] += v.y * v.y;
        sq[(j * 4 + 2) & 7] += v.z * v.z;
        sq[(j * 4 + 3) & 7] += v.w * v.w;
    }
#pragma unroll
    for (int k = 0; k < 8; ++k) {
        float v = sq[k];
        v += __shfl_xor(v, 1);  v += __shfl_xor(v, 2);  v += __shfl_xor(v, 4);
        v += __shfl_xor(v, 8);  v += __shfl_xor(v, 16); v += __shfl_xor(v, 32);
        sq[k] = v;
    }
    int lane = t & 63, wv = t >> 6;
    if (lane == 0) {
#pragma unroll
        for (int k = 0; k < 8; ++k) red[wv][k] = sq[k];
    }
    __syncthreads();
    if (t < 8) {
        float s = red[0][t] + red[1][t] + red[2][t] + red[3][t];
        inv_norm[b * 8 + t] = 1.0f / sqrtf(s);
    }
}

// ---------------------------------------------------------------------------
// 7) edge kernel: wave handles 8 edges of one batch; q row lives in 64 VGPRs.
__global__ __launch_bounds__(256) void edge_k(const int* __restrict__ idxs,
                                              const float* __restrict__ node_h,
                                              const float* __restrict__ q_h,
                                              const float* __restrict__ inv_norm,
                                              float* __restrict__ out) {
    int t = threadIdx.x;
    int lane = t & 63;
    int gw = blockIdx.x * 4 + (t >> 6);   // 0..4095
    int m0 = gw * 8;
    int b = m0 >> 9;                       // edges sorted by batch: m//E

    // lane l holds q_h[b][l*64 .. l*64+63]  (h = l*8+i, k = 0..7)
    const float* qrow = q_h + (size_t)b * 4096 + lane * 64;
    float q[64];
#pragma unroll
    for (int i = 0; i < 16; ++i) {
        float4 v = *(const float4*)(qrow + i * 4);
        q[i * 4 + 0] = v.x; q[i * 4 + 1] = v.y; q[i * 4 + 2] = v.z; q[i * 4 + 3] = v.w;
    }
    float4 inv0 = *(const float4*)(inv_norm + b * 8);
    float4 inv1 = *(const float4*)(inv_norm + b * 8 + 4);
    const float* nb = node_h + (size_t)b * 64 * 512;

#pragma unroll 2
    for (int e = 0; e < 8; ++e) {
        int m = m0 + e;
        int idx = idxs[m];
        int r = idx & 4095;
        int src = r >> 6, dst = r & 63;
        const float* sp = nb + (size_t)src * 512 + lane * 8;
        const float* dp = nb + (size_t)dst * 512 + lane * 8;
        float4 s0 = *(const float4*)(sp), s1 = *(const float4*)(sp + 4);
        float4 d0 = *(const float4*)(dp), d1 = *(const float4*)(dp + 4);
        float obj[8] = {s0.x + d0.x, s0.y + d0.y, s0.z + d0.z, s0.w + d0.w,
                        s1.x + d1.x, s1.y + d1.y, s1.z + d1.z, s1.w + d1.w};
        float acc[8] = {0.f, 0.f, 0.f, 0.f, 0.f, 0.f, 0.f, 0.f};
#pragma unroll
        for (int i = 0; i < 8; ++i)
#pragma unroll
            for (int k = 0; k < 8; ++k)
                acc[k] = fmaf(obj[i], q[i * 8 + k], acc[k]);
#pragma unroll
        for (int k = 0; k < 8; ++k) {
            float v = acc[k];
            v += __shfl_xor(v, 1);  v += __shfl_xor(v, 2);  v += __shfl_xor(v, 4);
            v += __shfl_xor(v, 8);  v += __shfl_xor(v, 16); v += __shfl_xor(v, 32);
            acc[k] = v;
        }
        if (lane == 0) {
            float4 o0 = {acc[0] * inv0.x, acc[1] * inv0.y, acc[2] * inv0.z, acc[3] * inv0.w};
            float4 o1 = {acc[4] * inv1.x, acc[5] * inv1.y, acc[6] * inv1.z, acc[7] * inv1.w};
            *(float4*)(out + (size_t)m * 8) = o0;
            *(float4*)(out + (size_t)m * 8 + 4) = o1;
        }
    }
}

// ---------------------------------------------------------------------------
extern "C" void kernel_launch(void* const* d_in, const int* in_sizes, int n_in,
                              void* d_out, int out_size, void* d_ws, size_t ws_size,
                              hipStream_t stream) {
    const float* node_feats = (const float*)d_in[0];  // [64][64][2048]
    const float* q_feats    = (const float*)d_in[1];  // [64][1024]
    const int*   indexes    = (const int*)d_in[2];    // [32768]
    const float* W_obj      = (const float*)d_in[3];  // [2048][512]
    const float* b_obj      = (const float*)d_in[4];  // [512]
    const float* W_q        = (const float*)d_in[5];  // [1024][4096]
    const float* b_q        = (const float*)d_in[6];  // [4096]
    float* out = (float*)d_out;                       // [32768][8]

    char* ws = (char*)d_ws;
    // A bf16 region (16.78MB) is reused as gemm2 partials (4MB) after gemm1.
    unsigned short* A_bf16 = (unsigned short*)(ws + 0);
    unsigned short* W_T    = (unsigned short*)(ws + 16777216);
    float* node_h          = (float*)(ws + 18874368);  // 8.39MB
    float* q_h             = (float*)(ws + 27262976);  // 1.05MB
    float* inv_norm        = (float*)(ws + 28311552);  // 2KB
    float* part            = (float*)(ws + 0);         // aliases A_bf16

    cvt_a<<<2048, 256, 0, stream>>>(node_feats, A_bf16);
    cvt_bt<<<dim3(64, 16), 256, 0, stream>>>(W_obj, W_T);
    gemm1<<<256, 512, 0, stream>>>(A_bf16, W_T, b_obj, node_h);
    gemm2<<<dim3(4, 16, 4), 256, 0, stream>>>(q_feats, W_q, part);  // after gemm1 (aliasing)
    finish_q<<<256, 256, 0, stream>>>(part, b_q, q_h);
    norms_k<<<64, 256, 0, stream>>>(q_h, inv_norm);
    edge_k<<<1024, 256, 0, stream>>>(indexes, node_h, q_h, inv_norm, out);
}

// Round 4
// 95.583 us; speedup vs baseline: 1.1164x; 1.1064x over previous
//
#include <hip/hip_runtime.h>
#include <hip/hip_bf16.h>

// Problem constants (EdgeQProj): B=64, N=64, E=512, OBJ_DIM=2048, Q_DIM=1024,
// HID=512, KS=8. M_edges = B*E = 32768.

using bf16x8 = __attribute__((ext_vector_type(8))) __bf16;
using f32x4  = __attribute__((ext_vector_type(4))) float;

__device__ __forceinline__ unsigned short f2bf(float f) {
    unsigned int u = __float_as_uint(f);
    unsigned int r = (u + 0x7FFFu + ((u >> 16) & 1u)) >> 16;  // RNE
    return (unsigned short)r;
}

__device__ __forceinline__ uint4 pack8(float4 a, float4 b) {
    union { unsigned short us[8]; uint4 u4; } r;
    r.us[0] = f2bf(a.x); r.us[1] = f2bf(a.y); r.us[2] = f2bf(a.z); r.us[3] = f2bf(a.w);
    r.us[4] = f2bf(b.x); r.us[5] = f2bf(b.y); r.us[6] = f2bf(b.z); r.us[7] = f2bf(b.w);
    return r.u4;
}

// ---------------------------------------------------------------------------
// 1) W_obj fp32 [2048][512] -> W_T bf16 [512][2048]  (tiled transpose)
__global__ __launch_bounds__(256) void cvt_bt(const float* __restrict__ W,
                                              unsigned short* __restrict__ WT) {
    __shared__ float lds[32][33];
    int k0 = blockIdx.x * 32, n0 = blockIdx.y * 32;
    int tx = threadIdx.x & 31, ty = threadIdx.x >> 5;  // ty 0..7
#pragma unroll
    for (int j = 0; j < 4; ++j)
        lds[ty + j * 8][tx] = W[(size_t)(k0 + ty + j * 8) * 512 + n0 + tx];
    __syncthreads();
#pragma unroll
    for (int j = 0; j < 4; ++j)
        WT[(size_t)(n0 + ty + j * 8) * 2048 + k0 + tx] = f2bf(lds[tx][ty + j * 8]);
}

// ---------------------------------------------------------------------------
// 2) GEMM1: node_h[4096][512] = relu(A_f32[4096][2048] @ W_T^T + b_obj)
//    fp32->bf16 convert FUSED into the A staging (kills the cvt_a pass).
//    BM=128 BN=64 BK=64 (2 ksubs of 32), 512 threads = 8 waves (4x2),
//    wave tile 32x32. Padded LDS rows (40 elems) -> 2-way aliasing (free).
#define LDK 40
__global__ __launch_bounds__(512, 2) void gemm1(const float* __restrict__ A32,
                                                const unsigned short* __restrict__ BT,
                                                const float* __restrict__ bias,
                                                float* __restrict__ C) {
    __shared__ __align__(16) unsigned short Asm[2][128][LDK];
    __shared__ __align__(16) unsigned short Bsm[2][64][LDK];

    // XCD-aware swizzle: grid=256 (%8==0, bijective). XCD x -> 32 consecutive
    // swz ids = 4 m-panels x full N  => A panels + B ~ L2-resident.
    int bid = blockIdx.x;
    int swz = (bid & 7) * 32 + (bid >> 3);
    int by = swz >> 3, bx = swz & 7;
    int m0 = by * 128, n0 = bx * 64;

    int t = threadIdx.x;
    int lane = t & 63, w = t >> 6;
    int wm = w >> 1, wn = w & 1;              // wave grid 4x2
    int l15 = lane & 15, l16 = lane >> 4;

    f32x4 acc[2][2];
#pragma unroll
    for (int i = 0; i < 2; ++i)
#pragma unroll
        for (int j = 0; j < 2; ++j) acc[i][j] = (f32x4){0.f, 0.f, 0.f, 0.f};

    for (int k0 = 0; k0 < 2048; k0 += 64) {
        // ---- stage A fp32->bf16 (1024 chunks of 8k) + B bf16 (512 chunks) --
#pragma unroll
        for (int j = 0; j < 2; ++j) {
            int c = j * 512 + t;
            int row = c >> 3, kc = c & 7;
            const float* src = A32 + (size_t)(m0 + row) * 2048 + k0 + kc * 8;
            float4 v0 = *(const float4*)(src);
            float4 v1 = *(const float4*)(src + 4);
            *(uint4*)(&Asm[kc >> 2][row][(kc & 3) * 8]) = pack8(v0, v1);
        }
        {
            int row = t >> 3, kc = t & 7;
            uint4 v = *(const uint4*)(BT + (size_t)(n0 + row) * 2048 + k0 + kc * 8);
            *(uint4*)(&Bsm[kc >> 2][row][(kc & 3) * 8]) = v;
        }
        __syncthreads();
        // ---- compute: 2 ksubs x (2x2) MFMAs ----
#pragma unroll
        for (int s = 0; s < 2; ++s) {
            bf16x8 a0 = *(const bf16x8*)(&Asm[s][wm * 32 + l15][l16 * 8]);
            bf16x8 a1 = *(const bf16x8*)(&Asm[s][wm * 32 + 16 + l15][l16 * 8]);
            bf16x8 b0 = *(const bf16x8*)(&Bsm[s][wn * 32 + l15][l16 * 8]);
            bf16x8 b1 = *(const bf16x8*)(&Bsm[s][wn * 32 + 16 + l15][l16 * 8]);
            acc[0][0] = __builtin_amdgcn_mfma_f32_16x16x32_bf16(a0, b0, acc[0][0], 0, 0, 0);
            acc[0][1] = __builtin_amdgcn_mfma_f32_16x16x32_bf16(a0, b1, acc[0][1], 0, 0, 0);
            acc[1][0] = __builtin_amdgcn_mfma_f32_16x16x32_bf16(a1, b0, acc[1][0], 0, 0, 0);
            acc[1][1] = __builtin_amdgcn_mfma_f32_16x16x32_bf16(a1, b1, acc[1][1], 0, 0, 0);
        }
        __syncthreads();
    }
    // ---- epilogue: bias + relu; D layout col=lane&15, row=(lane>>4)*4+j ----
#pragma unroll
    for (int fm = 0; fm < 2; ++fm)
#pragma unroll
        for (int fn = 0; fn < 2; ++fn) {
            int col = n0 + wn * 32 + fn * 16 + l15;
            float bv = bias[col];
#pragma unroll
            for (int j = 0; j < 4; ++j) {
                int row = m0 + wm * 32 + fm * 16 + l16 * 4 + j;
                float v = acc[fm][fn][j] + bv;
                C[(size_t)row * 512 + col] = v > 0.f ? v : 0.f;
            }
        }
}

// ---------------------------------------------------------------------------
// 3) GEMM2 (fused fp32->bf16 MFMA, single-pass W_q):
//    part[z][64][4096] = q[64][k0:k0+128] @ W_q[k0:k0+128][c0:c0+128]
//    grid (32 colblocks, 8 ksplits) = 256 blocks x 256 thr (4 waves).
//    Each W_q element is read by exactly ONE block (no redundant traffic).
//    W staged transposed+converted: Bsm[c][k] bf16, pad 136 -> even banks.
#define LDK2 136
__global__ __launch_bounds__(256) void gemm2(const float* __restrict__ qf,
                                             const float* __restrict__ Wq,
                                             float* __restrict__ part) {
    __shared__ __align__(16) unsigned short Asm[64][LDK2];   // q tile  [m][k]
    __shared__ __align__(16) unsigned short Bsm[128][LDK2];  // W tile  [c][k]

    int t = threadIdx.x;
    int lane = t & 63, w = t >> 6;          // 4 waves, wave owns 32 cols
    int l15 = lane & 15, l16 = lane >> 4;
    int c0 = blockIdx.x * 128;
    int k0 = blockIdx.y * 128;

    // ---- stage A: q[64][k0:k0+128] fp32 -> bf16 ----
#pragma unroll
    for (int j = 0; j < 4; ++j) {
        int g = t + j * 256;                 // 1024 chunks of 8k
        int row = g >> 4, kc = g & 15;
        const float* src = qf + (size_t)row * 1024 + k0 + kc * 8;
        float4 v0 = *(const float4*)(src);
        float4 v1 = *(const float4*)(src + 4);
        *(uint4*)(&Asm[row][kc * 8]) = pack8(v0, v1);
    }
    // ---- stage B: W_q[k0:k0+128][c0:c0+128] fp32 -> bf16, transposed ----
#pragma unroll
    for (int j = 0; j < 2; ++j) {
        int g = t + j * 256;                 // 512 units of 8k x 4c
        int kg = g >> 5, cg = g & 31;
        f32x4 wv[8];
#pragma unroll
        for (int kk = 0; kk < 8; ++kk)
            wv[kk] = *(const f32x4*)(Wq + (size_t)(k0 + kg * 8 + kk) * 4096 + c0 + cg * 4);
#pragma unroll
        for (int cc = 0; cc < 4; ++cc) {
            union { unsigned short us[8]; uint4 u4; } p;
#pragma unroll
            for (int kk = 0; kk < 8; ++kk) p.us[kk] = f2bf(wv[kk][cc]);
            *(uint4*)(&Bsm[cg * 4 + cc][kg * 8]) = p.u4;
        }
    }
    __syncthreads();

    // ---- MFMA: wave w covers cols [w*32, w*32+32); 4m x 2n x 4k frags ----
    f32x4 acc[4][2];
#pragma unroll
    for (int i = 0; i < 4; ++i)
#pragma unroll
        for (int j = 0; j < 2; ++j) acc[i][j] = (f32x4){0.f, 0.f, 0.f, 0.f};

#pragma unroll
    for (int ks = 0; ks < 4; ++ks) {
        bf16x8 bfr[2];
#pragma unroll
        for (int jn = 0; jn < 2; ++jn)
            bfr[jn] = *(const bf16x8*)(&Bsm[w * 32 + jn * 16 + l15][ks * 32 + l16 * 8]);
#pragma unroll
        for (int i = 0; i < 4; ++i) {
            bf16x8 afr = *(const bf16x8*)(&Asm[i * 16 + l15][ks * 32 + l16 * 8]);
            acc[i][0] = __builtin_amdgcn_mfma_f32_16x16x32_bf16(afr, bfr[0], acc[i][0], 0, 0, 0);
            acc[i][1] = __builtin_amdgcn_mfma_f32_16x16x32_bf16(afr, bfr[1], acc[i][1], 0, 0, 0);
        }
    }

    // ---- write partials ----
    float* pz = part + (size_t)blockIdx.y * 262144;
#pragma unroll
    for (int i = 0; i < 4; ++i)
#pragma unroll
        for (int jn = 0; jn < 2; ++jn) {
            int col = c0 + w * 32 + jn * 16 + l15;
#pragma unroll
            for (int j = 0; j < 4; ++j) {
                int row = i * 16 + l16 * 4 + j;
                pz[(size_t)row * 4096 + col] = acc[i][jn][j];
            }
        }
}

// 4) reduce partials + bias + relu -> q_h[64][4096]
__global__ __launch_bounds__(256) void finish_q(const float* __restrict__ part,
                                                const float* __restrict__ bq,
                                                float* __restrict__ q_h) {
    int base = (blockIdx.x * 256 + threadIdx.x) * 4;
    f32x4 a = (f32x4){0.f, 0.f, 0.f, 0.f};
#pragma unroll
    for (int s = 0; s < 8; ++s) a += *(const f32x4*)(part + (size_t)s * 262144 + base);
    f32x4 bb = *(const f32x4*)(bq + (base & 4095));
#pragma unroll
    for (int j = 0; j < 4; ++j) {
        float v = a[j] + bb[j];
        a[j] = v > 0.f ? v : 0.f;
    }
    *(f32x4*)(q_h + base) = a;
}

// 5) inv_norm[b][k] = 1/sqrt(sum_h q_h[b][h*8+k]^2)
__global__ __launch_bounds__(256) void norms_k(const float* __restrict__ q_h,
                                               float* __restrict__ inv_norm) {
    __shared__ float red[4][8];
    int b = blockIdx.x, t = threadIdx.x;
    const float* row = q_h + (size_t)b * 4096 + t * 16;
    float sq[8] = {0.f, 0.f, 0.f, 0.f, 0.f, 0.f, 0.f, 0.f};
#pragma unroll
    for (int j = 0; j < 4; ++j) {
        float4 v = *(const float4*)(row + j * 4);
        sq[(j * 4 + 0) & 7] += v.x * v.x;
        sq[(j * 4 + 1) & 7] += v.y * v.y;
        sq[(j * 4 + 2) & 7] += v.z * v.z;
        sq[(j * 4 + 3) & 7] += v.w * v.w;
    }
#pragma unroll
    for (int k = 0; k < 8; ++k) {
        float v = sq[k];
        v += __shfl_xor(v, 1);  v += __shfl_xor(v, 2);  v += __shfl_xor(v, 4);
        v += __shfl_xor(v, 8);  v += __shfl_xor(v, 16); v += __shfl_xor(v, 32);
        sq[k] = v;
    }
    int lane = t & 63, wv = t >> 6;
    if (lane == 0) {
#pragma unroll
        for (int k = 0; k < 8; ++k) red[wv][k] = sq[k];
    }
    __syncthreads();
    if (t < 8) {
        float s = red[0][t] + red[1][t] + red[2][t] + red[3][t];
        inv_norm[b * 8 + t] = 1.0f / sqrtf(s);
    }
}

// ---------------------------------------------------------------------------
// 6) edge kernel: wave handles 8 edges of one batch; q row lives in 64 VGPRs.
__global__ __launch_bounds__(256) void edge_k(const int* __restrict__ idxs,
                                              const float* __restrict__ node_h,
                                              const float* __restrict__ q_h,
                                              const float* __restrict__ inv_norm,
                                              float* __restrict__ out) {
    int t = threadIdx.x;
    int lane = t & 63;
    int gw = blockIdx.x * 4 + (t >> 6);   // 0..4095
    int m0 = gw * 8;
    int b = m0 >> 9;                       // edges sorted by batch: m//E

    // lane l holds q_h[b][l*64 .. l*64+63]  (h = l*8+i, k = 0..7)
    const float* qrow = q_h + (size_t)b * 4096 + lane * 64;
    float q[64];
#pragma unroll
    for (int i = 0; i < 16; ++i) {
        float4 v = *(const float4*)(qrow + i * 4);
        q[i * 4 + 0] = v.x; q[i * 4 + 1] = v.y; q[i * 4 + 2] = v.z; q[i * 4 + 3] = v.w;
    }
    float4 inv0 = *(const float4*)(inv_norm + b * 8);
    float4 inv1 = *(const float4*)(inv_norm + b * 8 + 4);
    const float* nb = node_h + (size_t)b * 64 * 512;

#pragma unroll 2
    for (int e = 0; e < 8; ++e) {
        int m = m0 + e;
        int idx = idxs[m];
        int r = idx & 4095;
        int src = r >> 6, dst = r & 63;
        const float* sp = nb + (size_t)src * 512 + lane * 8;
        const float* dp = nb + (size_t)dst * 512 + lane * 8;
        float4 s0 = *(const float4*)(sp), s1 = *(const float4*)(sp + 4);
        float4 d0 = *(const float4*)(dp), d1 = *(const float4*)(dp + 4);
        float obj[8] = {s0.x + d0.x, s0.y + d0.y, s0.z + d0.z, s0.w + d0.w,
                        s1.x + d1.x, s1.y + d1.y, s1.z + d1.z, s1.w + d1.w};
        float acc[8] = {0.f, 0.f, 0.f, 0.f, 0.f, 0.f, 0.f, 0.f};
#pragma unroll
        for (int i = 0; i < 8; ++i)
#pragma unroll
            for (int k = 0; k < 8; ++k)
                acc[k] = fmaf(obj[i], q[i * 8 + k], acc[k]);
#pragma unroll
        for (int k = 0; k < 8; ++k) {
            float v = acc[k];
            v += __shfl_xor(v, 1);  v += __shfl_xor(v, 2);  v += __shfl_xor(v, 4);
            v += __shfl_xor(v, 8);  v += __shfl_xor(v, 16); v += __shfl_xor(v, 32);
            acc[k] = v;
        }
        if (lane == 0) {
            float4 o0 = {acc[0] * inv0.x, acc[1] * inv0.y, acc[2] * inv0.z, acc[3] * inv0.w};
            float4 o1 = {acc[4] * inv1.x, acc[5] * inv1.y, acc[6] * inv1.z, acc[7] * inv1.w};
            *(float4*)(out + (size_t)m * 8) = o0;
            *(float4*)(out + (size_t)m * 8 + 4) = o1;
        }
    }
}

// ---------------------------------------------------------------------------
extern "C" void kernel_launch(void* const* d_in, const int* in_sizes, int n_in,
                              void* d_out, int out_size, void* d_ws, size_t ws_size,
                              hipStream_t stream) {
    const float* node_feats = (const float*)d_in[0];  // [64][64][2048]
    const float* q_feats    = (const float*)d_in[1];  // [64][1024]
    const int*   indexes    = (const int*)d_in[2];    // [32768]
    const float* W_obj      = (const float*)d_in[3];  // [2048][512]
    const float* b_obj      = (const float*)d_in[4];  // [512]
    const float* W_q        = (const float*)d_in[5];  // [1024][4096]
    const float* b_q        = (const float*)d_in[6];  // [4096]
    float* out = (float*)d_out;                       // [32768][8]

    char* ws = (char*)d_ws;
    unsigned short* W_T = (unsigned short*)(ws + 0);          // 2.10MB
    float* node_h       = (float*)(ws + 2097152);             // 8.39MB
    float* part         = (float*)(ws + 10485760);            // 8.39MB
    float* q_h          = (float*)(ws + 18874368);            // 1.05MB
    float* inv_norm     = (float*)(ws + 19922944);            // 2KB

    cvt_bt<<<dim3(64, 16), 256, 0, stream>>>(W_obj, W_T);
    gemm1<<<256, 512, 0, stream>>>(node_feats, W_T, b_obj, node_h);
    gemm2<<<dim3(32, 8), 256, 0, stream>>>(q_feats, W_q, part);
    finish_q<<<256, 256, 0, stream>>>(part, b_q, q_h);
    norms_k<<<64, 256, 0, stream>>>(q_h, inv_norm);
    edge_k<<<1024, 256, 0, stream>>>(indexes, node_h, q_h, inv_norm, out);
}